// Round 1
// baseline (649.513 us; speedup 1.0000x reference)
//
#include <hip/hip_runtime.h>
#include <cstdint>

// Problem constants
#define BB 64
#define SS 512
#define TT 32
#define DD 1024
#define MM (BB*SS)   // 32768 rows

// ---------------------------------------------------------------------------
// Kernel 1: emissions GEMM.  part-free version: each block computes a 128-row
// M-tile of C[32768][32] = A[32768][1024] @ W[1024][32].
// Block = 256 threads = 4 waves; wave w owns K-quarter [w*256, w*256+256).
// Per wave: LDS holds transposed feat chunk sFT[k][128(+4)] and W chunk
// sW[k][32(+4)].  Thread tile 8 rows x 8 cols (lane: rq=lane&15 -> rows
// rq*8.., cq=lane>>4 -> cols cq*8..).  Register-staged double buffering.
// Epilogue: LDS reduction of the 4 K-partials, single fp32 C written to ws.
// ---------------------------------------------------------------------------
#define GM 128
#define SFT_LD 132            // 128 + 4 pad (floats)
#define SW_LD 36              // 32 + 4 pad
#define WAVE_SMEM (32*SFT_LD + 32*SW_LD)   // 4224 + 1152 = 5376 floats

__global__ __launch_bounds__(256, 1) void gemm_emit(
    const float* __restrict__ A,    // [32768][1024]
    const float* __restrict__ W,    // [1024][32]
    float* __restrict__ C)          // [32768][32]  (workspace)
{
    __shared__ float smem[4 * WAVE_SMEM];   // 86016 B

    const int tid  = threadIdx.x;
    const int w    = tid >> 6;     // wave id 0..3  -> K-quarter
    const int lane = tid & 63;
    const int row0 = blockIdx.x * GM;
    const int kbase0 = w * 256;

    const int rq = lane & 15;      // 16 row groups of 8
    const int cq = lane >> 4;      // 4 col groups of 8
    const int r0 = rq * 8;
    const int c0 = cq * 8;

    float* sft = &smem[w * WAVE_SMEM];            // [32][SFT_LD]
    float* sw  = &smem[w * WAVE_SMEM + 32*SFT_LD];// [32][SW_LD]

    float4 fst[16];
    float4 wst[4];

    auto issue_loads = [&](int ch) {
        const int kb = kbase0 + ch * 32;
#pragma unroll
        for (int i = 0; i < 16; ++i) {
            int f  = lane + 64 * i;        // 0..1023
            int r  = f >> 3;               // 0..127
            int kk = (f & 7) * 4;          // 0..28
            fst[i] = *(const float4*)&A[(size_t)(row0 + r) * DD + kb + kk];
        }
#pragma unroll
        for (int i = 0; i < 4; ++i) {
            int f  = lane + 64 * i;        // 0..255
            int k  = f >> 3;               // 0..31
            int c4 = (f & 7) * 4;          // 0..28
            wst[i] = *(const float4*)&W[(size_t)(kb + k) * TT + c4];
        }
    };
    auto write_lds = [&]() {
#pragma unroll
        for (int i = 0; i < 16; ++i) {
            int f  = lane + 64 * i;
            int r  = f >> 3;
            int kk = (f & 7) * 4;
            sft[(kk + 0) * SFT_LD + r] = fst[i].x;
            sft[(kk + 1) * SFT_LD + r] = fst[i].y;
            sft[(kk + 2) * SFT_LD + r] = fst[i].z;
            sft[(kk + 3) * SFT_LD + r] = fst[i].w;
        }
#pragma unroll
        for (int i = 0; i < 4; ++i) {
            int f  = lane + 64 * i;
            int k  = f >> 3;
            int c4 = (f & 7) * 4;
            *(float4*)&sw[k * SW_LD + c4] = wst[i];
        }
    };

    float acc[8][8];
#pragma unroll
    for (int a = 0; a < 8; ++a)
#pragma unroll
        for (int b = 0; b < 8; ++b) acc[a][b] = 0.f;

    issue_loads(0);
    write_lds();
    __syncthreads();

    for (int ch = 0; ch < 8; ++ch) {
        if (ch < 7) issue_loads(ch + 1);
#pragma unroll
        for (int k = 0; k < 32; ++k) {
            float4 a0 = *(const float4*)&sft[k * SFT_LD + r0];
            float4 a1 = *(const float4*)&sft[k * SFT_LD + r0 + 4];
            float4 w0 = *(const float4*)&sw[k * SW_LD + c0];
            float4 w1 = *(const float4*)&sw[k * SW_LD + c0 + 4];
            float ar[8] = {a0.x, a0.y, a0.z, a0.w, a1.x, a1.y, a1.z, a1.w};
            float wc[8] = {w0.x, w0.y, w0.z, w0.w, w1.x, w1.y, w1.z, w1.w};
#pragma unroll
            for (int rr = 0; rr < 8; ++rr)
#pragma unroll
                for (int cc = 0; cc < 8; ++cc)
                    acc[rr][cc] = fmaf(ar[rr], wc[cc], acc[rr][cc]);
        }
        __syncthreads();
        if (ch < 7) write_lds();
        __syncthreads();
    }

    // ---- cross-wave K reduction via LDS, then write C ----
    float* red = smem;   // reuse: [4 waves][64 lanes][64 vals] = 16384 floats
#pragma unroll
    for (int rr = 0; rr < 8; ++rr)
#pragma unroll
        for (int cc = 0; cc < 8; ++cc)
            red[tid * 64 + rr * 8 + cc] = acc[rr][cc];
    __syncthreads();

#pragma unroll
    for (int u = 0; u < 16; ++u) {
        int o   = tid * 16 + u;          // 0..4095 within tile
        int row = o >> 5;                // 0..127
        int col = o & 31;
        int sl  = (row >> 3) + ((col >> 3) << 4);   // source lane
        int ii  = (row & 7) * 8 + (col & 7);
        float s = red[(0 * 64 + sl) * 64 + ii]
                + red[(1 * 64 + sl) * 64 + ii]
                + red[(2 * 64 + sl) * 64 + ii]
                + red[(3 * 64 + sl) * 64 + ii];
        C[(size_t)(row0 + row) * TT + col] = s;
    }
}

// ---------------------------------------------------------------------------
// Kernel 2: CRF score + forward recurrence + logZ, one wave per batch.
// Exp-space forward: A[j]=exp(alpha[j]-c); per step a plain 32-FMA matvec
// with ET=exp(trans) columns held in registers; broadcast via v_readlane.
// Emissions for the whole sequence staged in 64 KB LDS.
// ---------------------------------------------------------------------------
__device__ __forceinline__ float rl(float v, int l) {
    return __uint_as_float(__builtin_amdgcn_readlane(__float_as_uint(v), l));
}

__global__ __launch_bounds__(64) void crf_forward(
    const float* __restrict__ emis,    // [64][512][32] (workspace)
    const float* __restrict__ bias,    // [32]
    const int*   __restrict__ tags,    // [64][512]
    const float* __restrict__ start_t, // [32]
    const float* __restrict__ end_t,   // [32]
    const float* __restrict__ trans,   // [32][32]
    float* __restrict__ out)
{
    __shared__ float e_lds[SS * TT];   // 64 KB

    const int b    = blockIdx.x;
    const int lane = threadIdx.x;      // 0..63
    const float* eb = emis + (size_t)b * SS * TT;
    const int*   tb = tags + b * SS;

    // stage emissions (+bias) into LDS
    float4 bias4 = *(const float4*)&bias[(lane * 4) & 31];
    for (int i = 0; i < 64; ++i) {
        int idx = (i * 64 + lane) * 4;
        float4 v = *(const float4*)&eb[idx];
        v.x += bias4.x; v.y += bias4.y; v.z += bias4.z; v.w += bias4.w;
        *(float4*)&e_lds[idx] = v;
    }
    __syncthreads();

    // sequence length = index of first -1 tag (mask is a prefix)
    int fneg = SS;
    for (int t = lane; t < SS; t += 64)
        if (tb[t] < 0) fneg = min(fneg, t);
#pragma unroll
    for (int off = 32; off; off >>= 1)
        fneg = min(fneg, __shfl_xor(fneg, off));
    const int len = fneg;   // >= 256 per problem setup

    // ---- numerator score ----
    float sc = 0.f;
    for (int t = lane; t < len; t += 64) {
        int tg = tb[t];
        float e = e_lds[t * TT + tg];
        if (t == 0) sc += start_t[tg] + e;
        else        sc += trans[tb[t - 1] * TT + tg] + e;
    }
#pragma unroll
    for (int off = 32; off; off >>= 1) sc += __shfl_xor(sc, off);
    const float score = sc + end_t[tb[len - 1]];

    // ---- forward recurrence in exp space ----
    const int j = lane & 31;
    float et[32];
#pragma unroll
    for (int i = 0; i < 32; ++i) et[i] = __expf(trans[i * TT + j]);

    float a0 = start_t[j] + e_lds[j];
    float m = a0;
#pragma unroll
    for (int off = 16; off; off >>= 1) m = fmaxf(m, __shfl_xor(m, off));
    float Aj = __expf(a0 - m);
    float c = m;

    for (int t = 1; t < len; ++t) {
        float s0 = 0.f, s1 = 0.f, s2 = 0.f, s3 = 0.f;
#pragma unroll
        for (int i = 0; i < 32; i += 4) {
            s0 = fmaf(rl(Aj, i + 0), et[i + 0], s0);
            s1 = fmaf(rl(Aj, i + 1), et[i + 1], s1);
            s2 = fmaf(rl(Aj, i + 2), et[i + 2], s2);
            s3 = fmaf(rl(Aj, i + 3), et[i + 3], s3);
        }
        float Sj = (s0 + s1) + (s2 + s3);
        float v  = Sj * __expf(e_lds[t * TT + j]);
        float M = v;
#pragma unroll
        for (int off = 16; off; off >>= 1) M = fmaxf(M, __shfl_xor(M, off));
        Aj = v / M;
        c += __logf(M);
    }

    float z = Aj * __expf(end_t[j]);
#pragma unroll
    for (int off = 16; off; off >>= 1) z += __shfl_xor(z, off);
    const float log_z = c + __logf(z);

    if (lane == 0)
        atomicAdd(out, (log_z - score) * (1.0f / BB));   // -llh/B
}

// ---------------------------------------------------------------------------
extern "C" void kernel_launch(void* const* d_in, const int* in_sizes, int n_in,
                              void* d_out, int out_size, void* d_ws, size_t ws_size,
                              hipStream_t stream) {
    const float* feat = (const float*)d_in[0];
    const int*   tags = (const int*)  d_in[1];
    const float* W    = (const float*)d_in[2];
    const float* bias = (const float*)d_in[3];
    const float* st   = (const float*)d_in[4];
    const float* en   = (const float*)d_in[5];
    const float* tr   = (const float*)d_in[6];
    float* out  = (float*)d_out;
    float* emis = (float*)d_ws;    // 32768*32 floats = 4 MB

    hipMemsetAsync(out, 0, sizeof(float), stream);
    gemm_emit<<<MM / GM, 256, 0, stream>>>(feat, W, emis);
    crf_forward<<<BB, 64, 0, stream>>>(emis, bias, tags, st, en, tr, out);
}

// Round 2
// 561.037 us; speedup vs baseline: 1.1577x; 1.1577x over previous
//
#include <hip/hip_runtime.h>
#include <cstdint>

#define BB 64
#define SS 512
#define TT 32
#define DD 1024
#define MM (BB*SS)   // 32768 rows

// ---------------------------------------------------------------------------
// Kernel 1: emissions GEMM  C[32768][32] = A[32768][1024] @ W[1024][32]
// grid 512, block 256 (4 waves). Block tile = 64 rows. Wave w owns K-quarter
// [w*256, w*256+256), processed in 8 chunks of 32 k. Per-wave-private LDS
// buffers (A 64x32 f32 = 8 KB, W 32x32 = 4 KB), filled by global_load_lds
// width-16 (no VGPR staging). A chunk stored row-major with XOR-swizzled
// 16B slots (slot = k4 ^ rowgroup) via pre-swizzled GLOBAL source addresses
// so per-thread 8-row ds_read_b128 at fixed k4 is bank-conflict-free.
// No __syncthreads in main loop (per-wave buffers + vmcnt/lgkmcnt fences).
// Epilogue: 4-wave K-partial reduction through LDS, coalesced C write.
// ---------------------------------------------------------------------------
#define MT 64
#define KW 256
#define KC 32
#define NCH (KW/KC)

typedef __attribute__((address_space(3))) uint32_t lds_u32;
typedef __attribute__((address_space(1))) const uint32_t g_u32;

__device__ __forceinline__ void gload16(const float* g, float* l) {
    __builtin_amdgcn_global_load_lds((g_u32*)g, (lds_u32*)l, 16, 0, 0);
}

__global__ __launch_bounds__(256, 2) void gemm_emit(
    const float* __restrict__ A,    // [32768][1024]
    const float* __restrict__ Wg,   // [1024][32]
    float* __restrict__ C)          // [32768][32]
{
    __shared__ float smem[4 * 3072];   // per wave: A 2048 + W 1024 floats (48 KB)

    const int tid  = threadIdx.x;
    const int w    = tid >> 6;
    const int lane = tid & 63;
    const int row0 = blockIdx.x * MT;

    const int rq = lane & 7;    // row group (8 rows each)
    const int cq = lane >> 3;   // col group (4 cols each)
    const int Lhi = lane >> 3;  // staging: row within 8-row slab
    const int Llo = lane & 7;   // staging: 16B slot

    float* Ab = &smem[w * 3072];
    float* Wb = Ab + 2048;

    float acc[8][4];
#pragma unroll
    for (int a = 0; a < 8; ++a)
#pragma unroll
        for (int b = 0; b < 4; ++b) acc[a][b] = 0.f;

    auto issue = [&](int ch) {
        const int kb = w * KW + ch * KC;
        // A: 8 issues, instr i covers rows i*8..i*8+7; slot (L&7) holds
        // logical k4 = (L&7) ^ i  (inverse-swizzled source, linear LDS dest)
#pragma unroll
        for (int i = 0; i < 8; ++i)
            gload16(&A[(size_t)(row0 + i * 8 + Lhi) * DD + kb + ((Llo ^ i) << 2)],
                    Ab + i * 256);
        // W chunk [32 k][32 c] is contiguous in global: linear copy
#pragma unroll
        for (int i = 0; i < 4; ++i)
            gload16(&Wg[(size_t)kb * TT + i * 256 + lane * 4], Wb + i * 256);
    };

    issue(0);
    for (int ch = 0; ch < NCH; ++ch) {
        asm volatile("s_waitcnt vmcnt(0)" ::: "memory");
#pragma unroll
        for (int g = 0; g < 8; ++g) {          // k4 groups (4 k each)
            float4 wv[4];
#pragma unroll
            for (int kk = 0; kk < 4; ++kk)
                wv[kk] = *(const float4*)&Wb[(g * 4 + kk) * TT + cq * 4];
#pragma unroll
            for (int rr = 0; rr < 8; ++rr) {
                // row r = rq*8+rr; logical k4=g stored at slot g^rq
                float4 av = *(const float4*)&Ab[(rq * 8 + rr) * KC + ((g ^ rq) << 2)];
                float am[4] = {av.x, av.y, av.z, av.w};
#pragma unroll
                for (int kk = 0; kk < 4; ++kk) {
                    acc[rr][0] = fmaf(am[kk], wv[kk].x, acc[rr][0]);
                    acc[rr][1] = fmaf(am[kk], wv[kk].y, acc[rr][1]);
                    acc[rr][2] = fmaf(am[kk], wv[kk].z, acc[rr][2]);
                    acc[rr][3] = fmaf(am[kk], wv[kk].w, acc[rr][3]);
                }
            }
        }
        if (ch + 1 < NCH) {
            asm volatile("s_waitcnt lgkmcnt(0)" ::: "memory");  // ds_reads done -> buffer free
            issue(ch + 1);
        }
    }

    // ---- cross-wave K reduction ----
    __syncthreads();
    float* red = smem;                 // [256 tid][32 vals] = 32 KB
#pragma unroll
    for (int rr = 0; rr < 8; ++rr)
        *(float4*)&red[tid * 32 + rr * 4] =
            make_float4(acc[rr][0], acc[rr][1], acc[rr][2], acc[rr][3]);
    __syncthreads();

    const int r  = tid >> 2;           // 0..63
    const int cg = tid & 3;            // col octet
    const int idx = (r & 7) * 4;
    const int L1 = (cg * 2) * 8 + (r >> 3);
    const int L2 = (cg * 2 + 1) * 8 + (r >> 3);
    float4 o0 = make_float4(0, 0, 0, 0), o1 = o0;
#pragma unroll
    for (int ww = 0; ww < 4; ++ww) {
        float4 a4 = *(const float4*)&red[(ww * 64 + L1) * 32 + idx];
        float4 b4 = *(const float4*)&red[(ww * 64 + L2) * 32 + idx];
        o0.x += a4.x; o0.y += a4.y; o0.z += a4.z; o0.w += a4.w;
        o1.x += b4.x; o1.y += b4.y; o1.z += b4.z; o1.w += b4.w;
    }
    *(float4*)&C[(size_t)(row0 + r) * TT + cg * 8]     = o0;
    *(float4*)&C[(size_t)(row0 + r) * TT + cg * 8 + 4] = o1;
}

// ---------------------------------------------------------------------------
// Kernel 2: CRF score + forward recurrence, one wave per batch.
// Exp-space forward with renorm every 4 steps only: per step is 32
// readlane-FMAs (4 chains) + 1 exp + 1 mul. No per-step reduce, no division.
// ---------------------------------------------------------------------------
__device__ __forceinline__ float rl(float v, int l) {
    return __uint_as_float(__builtin_amdgcn_readlane(__float_as_uint(v), l));
}

__device__ __forceinline__ float stepf(float A, const float* et, float x) {
    float s0 = 0.f, s1 = 0.f, s2 = 0.f, s3 = 0.f;
#pragma unroll
    for (int i = 0; i < 32; i += 4) {
        s0 = fmaf(rl(A, i + 0), et[i + 0], s0);
        s1 = fmaf(rl(A, i + 1), et[i + 1], s1);
        s2 = fmaf(rl(A, i + 2), et[i + 2], s2);
        s3 = fmaf(rl(A, i + 3), et[i + 3], s3);
    }
    return ((s0 + s1) + (s2 + s3)) * x;
}

__global__ __launch_bounds__(64) void crf_forward(
    const float* __restrict__ emis,    // [64][512][32]
    const float* __restrict__ bias,    // [32]
    const int*   __restrict__ tags,    // [64][512]
    const float* __restrict__ start_t, // [32]
    const float* __restrict__ end_t,   // [32]
    const float* __restrict__ trans,   // [32][32]
    float* __restrict__ out)
{
    __shared__ float e_lds[SS * TT];   // 64 KB

    const int b    = blockIdx.x;
    const int lane = threadIdx.x;
    const float* eb = emis + (size_t)b * SS * TT;
    const int*   tb = tags + b * SS;

    // stage emissions (+bias) into LDS
    float4 bias4 = *(const float4*)&bias[(lane * 4) & 31];
    for (int i = 0; i < 64; ++i) {
        int idx = (i * 64 + lane) * 4;
        float4 v = *(const float4*)&eb[idx];
        v.x += bias4.x; v.y += bias4.y; v.z += bias4.z; v.w += bias4.w;
        *(float4*)&e_lds[idx] = v;
    }
    __syncthreads();

    // length = index of first -1 tag (mask is a prefix, len >= 256)
    int fneg = SS;
    for (int t = lane; t < SS; t += 64)
        if (tb[t] < 0) fneg = min(fneg, t);
#pragma unroll
    for (int off = 32; off; off >>= 1)
        fneg = min(fneg, __shfl_xor(fneg, off));
    const int len = fneg;

    // ---- numerator score ----
    float sc = 0.f;
    for (int t = lane; t < len; t += 64) {
        int tg = tb[t];
        float e = e_lds[t * TT + tg];
        if (t == 0) sc += start_t[tg] + e;
        else        sc += trans[tb[t - 1] * TT + tg] + e;
    }
#pragma unroll
    for (int off = 32; off; off >>= 1) sc += __shfl_xor(sc, off);
    const float score = sc + end_t[tb[len - 1]];

    // ---- forward recurrence, exp space, renorm every 4 steps ----
    const int j = lane & 31;
    float et[32];
#pragma unroll
    for (int i = 0; i < 32; ++i) et[i] = __expf(trans[i * TT + j]);

    float a0 = start_t[j] + e_lds[j];
    float m = a0;
#pragma unroll
    for (int off = 16; off; off >>= 1) m = fmaxf(m, __shfl_xor(m, off));
    float Aj = __expf(a0 - m);
    float c = m;

    int t = 1;
    for (; t + 4 <= len; t += 4) {
        float x0 = __expf(e_lds[(t + 0) * TT + j]);
        float x1 = __expf(e_lds[(t + 1) * TT + j]);
        float x2 = __expf(e_lds[(t + 2) * TT + j]);
        float x3 = __expf(e_lds[(t + 3) * TT + j]);
        Aj = stepf(Aj, et, x0);
        Aj = stepf(Aj, et, x1);
        Aj = stepf(Aj, et, x2);
        Aj = stepf(Aj, et, x3);
        float M = Aj;
#pragma unroll
        for (int off = 16; off; off >>= 1) M = fmaxf(M, __shfl_xor(M, off));
        Aj *= __builtin_amdgcn_rcpf(M);
        c += __logf(M);
    }
    for (; t < len; ++t) {           // <=3 tail steps, no renorm needed
        float x = __expf(e_lds[t * TT + j]);
        Aj = stepf(Aj, et, x);
    }

    float z = Aj * __expf(end_t[j]);
#pragma unroll
    for (int off = 16; off; off >>= 1) z += __shfl_xor(z, off);
    const float log_z = c + __logf(z);

    if (lane == 0)
        atomicAdd(out, (log_z - score) * (1.0f / BB));
}

// ---------------------------------------------------------------------------
extern "C" void kernel_launch(void* const* d_in, const int* in_sizes, int n_in,
                              void* d_out, int out_size, void* d_ws, size_t ws_size,
                              hipStream_t stream) {
    const float* feat = (const float*)d_in[0];
    const int*   tags = (const int*)  d_in[1];
    const float* W    = (const float*)d_in[2];
    const float* bias = (const float*)d_in[3];
    const float* st   = (const float*)d_in[4];
    const float* en   = (const float*)d_in[5];
    const float* tr   = (const float*)d_in[6];
    float* out  = (float*)d_out;
    float* emis = (float*)d_ws;    // 4 MB

    hipMemsetAsync(out, 0, sizeof(float), stream);
    gemm_emit<<<MM / MT, 256, 0, stream>>>(feat, W, emis);
    crf_forward<<<BB, 64, 0, stream>>>(emis, bias, tags, st, en, tr, out);
}

// Round 6
// 400.544 us; speedup vs baseline: 1.6216x; 1.4007x over previous
//
#include <hip/hip_runtime.h>
#include <cstdint>

#define BB 64
#define SS 512
#define TT 32
#define DD 1024
#define MM (BB*SS)     // 32768 rows
#define NC 32          // CRF chunks per batch
#define CHK 16         // steps per chunk

typedef __attribute__((address_space(3))) uint32_t lds_u32;
typedef __attribute__((address_space(1))) const uint32_t g_u32;

__device__ __forceinline__ void gload16(const float* g, float* l) {
    __builtin_amdgcn_global_load_lds((g_u32*)g, (lds_u32*)l, 16, 0, 0);
}
__device__ __forceinline__ float rl(float v, int l) {
    return __uint_as_float(__builtin_amdgcn_readlane(__float_as_uint(v), l));
}
// reduce within each 32-lane half: xor offsets <32 never cross the half
#define HALF_MAX(M) do { \
    M = fmaxf(M, __shfl_xor(M, 1));  \
    M = fmaxf(M, __shfl_xor(M, 2));  \
    M = fmaxf(M, __shfl_xor(M, 4));  \
    M = fmaxf(M, __shfl_xor(M, 8));  \
    M = fmaxf(M, __shfl_xor(M, 16)); } while(0)
#define HALF_SUM(M) do { \
    M += __shfl_xor(M, 1);  \
    M += __shfl_xor(M, 2);  \
    M += __shfl_xor(M, 4);  \
    M += __shfl_xor(M, 8);  \
    M += __shfl_xor(M, 16); } while(0)

// ---------------------------------------------------------------------------
// Kernel 1: emissions GEMM  emis[32768][32] = A[32768][1024] @ W[1024][32] + b
// grid 512, block 256 (4 waves), 64 rows/block; wave w owns K-quarter.
// Thread = one row (row = lane), all 32 cols in acc[32].
// A staged per-wave via global_load_lds w16, double-buffered, XOR-swizzled
// source -> conflict-free ds_read_b128.  W read as same-address broadcast
// v-loads (L1/L2-resident); sched_barrier(0) per k4 group caps clustering.
// Epilogue: 4-way K-partial reduction through LDS, coalesced C write.
// ---------------------------------------------------------------------------
__global__ __launch_bounds__(256, 2) void gemm_emit(
    const float* __restrict__ A, const float* __restrict__ Wg,
    const float* __restrict__ bias, float* __restrict__ C)
{
    __shared__ float smem[16384];     // 4 waves x dbuf x 2048 floats = 64 KB

    const int tid = threadIdx.x;
    const int w = tid >> 6, lane = tid & 63;
    const int row0 = blockIdx.x * 64;
    float* bufs = &smem[w * 4096];

    float acc[32];
#pragma unroll
    for (int q = 0; q < 32; ++q) acc[q] = 0.f;

    const int srck4 = (lane & 7) ^ (lane >> 3);   // inverse-swizzled source slot

    auto issue = [&](int ch) {
        const int kb = w * 256 + ch * 32;
        float* dst = bufs + (ch & 1) * 2048;
#pragma unroll
        for (int i = 0; i < 8; ++i)
            gload16(&A[(size_t)(row0 + i * 8 + (lane >> 3)) * DD + kb + srck4 * 4],
                    dst + i * 256);
    };

    issue(0);
#pragma unroll 1
    for (int ch = 0; ch < 8; ++ch) {
        if (ch < 7) {
            // prior iteration's ds_reads fully drained -> safe to overwrite buf
            asm volatile("s_waitcnt lgkmcnt(0)" ::: "memory");
            issue(ch + 1);
            asm volatile("s_waitcnt vmcnt(8)" ::: "memory");
        } else {
            asm volatile("s_waitcnt vmcnt(0)" ::: "memory");
        }
        const float* bc = bufs + (ch & 1) * 2048;
        const int kb = w * 256 + ch * 32;
        float4 av[8];
#pragma unroll
        for (int k4 = 0; k4 < 8; ++k4)
            av[k4] = *(const float4*)&bc[lane * 32 + ((k4 ^ (lane & 7)) << 2)];
#pragma unroll
        for (int k4 = 0; k4 < 8; ++k4) {
            float am[4] = {av[k4].x, av[k4].y, av[k4].z, av[k4].w};
#pragma unroll
            for (int kk = 0; kk < 4; ++kk) {
                const float* wrow = &Wg[(size_t)(kb + k4 * 4 + kk) * TT];
#pragma unroll
                for (int c8 = 0; c8 < 8; ++c8) {
                    float4 wv = *(const float4*)&wrow[c8 * 4];  // broadcast load
                    acc[c8*4+0] = fmaf(am[kk], wv.x, acc[c8*4+0]);
                    acc[c8*4+1] = fmaf(am[kk], wv.y, acc[c8*4+1]);
                    acc[c8*4+2] = fmaf(am[kk], wv.z, acc[c8*4+2]);
                    acc[c8*4+3] = fmaf(am[kk], wv.w, acc[c8*4+3]);
                }
            }
            __builtin_amdgcn_sched_barrier(0);   // cap W-load clustering
        }
    }

    // cross-wave K reduction (stride 36 breaks bank degeneracy)
    __syncthreads();
    float* red = smem;                 // 256*36 floats = 36 KB (reuse bufs)
#pragma unroll
    for (int q4 = 0; q4 < 8; ++q4)
        *(float4*)&red[tid * 36 + q4 * 4] =
            make_float4(acc[q4*4], acc[q4*4+1], acc[q4*4+2], acc[q4*4+3]);
    __syncthreads();

    const int r = tid >> 2, cg = tid & 3;
    float4 o0 = make_float4(0,0,0,0), o1 = o0;
#pragma unroll
    for (int ww = 0; ww < 4; ++ww) {
        const float* rb = &red[(ww * 64 + r) * 36 + cg * 8];
        float4 a4 = *(const float4*)&rb[0];
        float4 b4 = *(const float4*)&rb[4];
        o0.x += a4.x; o0.y += a4.y; o0.z += a4.z; o0.w += a4.w;
        o1.x += b4.x; o1.y += b4.y; o1.z += b4.z; o1.w += b4.w;
    }
    float4 bb0 = *(const float4*)&bias[cg * 8];
    float4 bb1 = *(const float4*)&bias[cg * 8 + 4];
    o0.x += bb0.x; o0.y += bb0.y; o0.z += bb0.z; o0.w += bb0.w;
    o1.x += bb1.x; o1.y += bb1.y; o1.z += bb1.z; o1.w += bb1.w;
    *(float4*)&C[(size_t)(row0 + r) * TT + cg * 8]     = o0;
    *(float4*)&C[(size_t)(row0 + r) * TT + cg * 8 + 4] = o1;
}

// ---------------------------------------------------------------------------
// Kernel 2: CRF phase 1 — chunk product matrices (parallel scan, phase A).
// grid 512 (8 blocks/batch), block 128 (4 half-waves); half-wave = one
// (batch, chunk): lane r holds row r of P (32 floats).
// Step: P <- P * (ET * diag(x_t)) — lane-local FMA; ET broadcast from LDS.
// Renorm by global max every 4 steps; per-chunk scalar log-scale in Ls.
// ---------------------------------------------------------------------------
__global__ __launch_bounds__(128) void crf_phase1(
    const float* __restrict__ emis, const int* __restrict__ tags,
    const float* __restrict__ trans, float* __restrict__ P, float* __restrict__ Ls)
{
    __shared__ float ex[4 * CHK * 32];   // 8 KB: 4 local chunks
    __shared__ float ET[32 * 32];        // 4 KB
    __shared__ int s_len;

    const int tid = threadIdx.x;
    const int b  = blockIdx.x >> 3;           // 8 blocks per batch
    const int c0 = (blockIdx.x & 7) * 4;      // first chunk of this block
    const int pl = tid >> 5;                  // local half-wave 0..3
    const int r  = tid & 31;                  // row of P
    const int c  = c0 + pl;                   // chunk id 0..31

    if (tid == 0) s_len = SS;
    __syncthreads();
    for (int t = tid; t < SS; t += 128)
        if (tags[b * SS + t] < 0) atomicMin(&s_len, t);
#pragma unroll
    for (int u = 0; u < 8; ++u) {
        int e = u * 128 + tid;
        ET[e] = __expf(trans[e]);
    }
    // stage exp(emissions) for the block's 4 chunks
#pragma unroll 1
    for (int u = 0; u < 16; ++u) {
        int e = u * 128 + tid;                // 0..2047
        int epl = e >> 9, s = (e >> 5) & 15, jj = e & 31;
        int t = (c0 + epl) * CHK + 1 + s;
        ex[e] = (t < SS) ? __expf(emis[((size_t)b * SS + t) * TT + jj]) : 1.0f;
    }
    __syncthreads();
    const int len = s_len;
    const float* exh = &ex[pl * (CHK * 32)];

    float p[32];
#pragma unroll
    for (int q = 0; q < 32; ++q) p[q] = (q == r) ? 1.f : 0.f;
    float cs = 0.f;

#pragma unroll 1
    for (int g = 0; g < 4; ++g) {
#pragma unroll 1
        for (int u = 0; u < 4; ++u) {
            const int s = g * 4 + u;
            if (c * CHK + 1 + s < len) {
                float pn[32];
#pragma unroll
                for (int q = 0; q < 32; ++q) pn[q] = 0.f;
#pragma unroll
                for (int i = 0; i < 32; ++i) {
                    float pi = p[i];
#pragma unroll
                    for (int q8 = 0; q8 < 8; ++q8) {
                        float4 et = *(const float4*)&ET[i * 32 + q8 * 4];
                        pn[q8*4+0] = fmaf(pi, et.x, pn[q8*4+0]);
                        pn[q8*4+1] = fmaf(pi, et.y, pn[q8*4+1]);
                        pn[q8*4+2] = fmaf(pi, et.z, pn[q8*4+2]);
                        pn[q8*4+3] = fmaf(pi, et.w, pn[q8*4+3]);
                    }
                    if (i & 1) __builtin_amdgcn_sched_barrier(0);  // cap clustering
                }
#pragma unroll
                for (int q8 = 0; q8 < 8; ++q8) {
                    float4 xv = *(const float4*)&exh[s * 32 + q8 * 4];
                    p[q8*4+0] = pn[q8*4+0] * xv.x;
                    p[q8*4+1] = pn[q8*4+1] * xv.y;
                    p[q8*4+2] = pn[q8*4+2] * xv.z;
                    p[q8*4+3] = pn[q8*4+3] * xv.w;
                }
            }
        }
        // renorm: lane-local max, then across the 32 rows
        float M = p[0];
#pragma unroll
        for (int q = 1; q < 32; ++q) M = fmaxf(M, p[q]);
        HALF_MAX(M);
        float rM = __builtin_amdgcn_rcpf(M);
#pragma unroll
        for (int q = 0; q < 32; ++q) p[q] *= rM;
        cs += __logf(M);
    }

    const int pair = b * NC + c;
#pragma unroll
    for (int q4 = 0; q4 < 8; ++q4)
        *(float4*)&P[((size_t)pair * 32 + r) * 32 + q4 * 4] =
            make_float4(p[q4*4], p[q4*4+1], p[q4*4+2], p[q4*4+3]);
    if (r == 0) Ls[pair] = cs;
}

// ---------------------------------------------------------------------------
// Kernel 3: CRF phase 2 — score + sequential chunk application + logZ.
// One wave per batch; P read directly from global (L2-hot, coalesced).
// ---------------------------------------------------------------------------
__global__ __launch_bounds__(64) void crf_phase2(
    const float* __restrict__ emis, const int* __restrict__ tags,
    const float* __restrict__ start_t, const float* __restrict__ end_t,
    const float* __restrict__ trans, const float* __restrict__ P,
    const float* __restrict__ Ls, float* __restrict__ out)
{
    const int b = blockIdx.x;
    const int lane = threadIdx.x, jj = lane & 31;
    const int* tb = tags + b * SS;

    // length (mask is a prefix)
    int fneg = SS;
    for (int t = lane; t < SS; t += 64)
        if (tb[t] < 0) fneg = min(fneg, t);
#pragma unroll
    for (int off = 32; off; off >>= 1)
        fneg = min(fneg, __shfl_xor(fneg, off));
    const int len = fneg;

    // numerator score (emis already includes bias)
    float sc = 0.f;
    for (int t = lane; t < len; t += 64) {
        int tg = tb[t];
        float e = emis[((size_t)b * SS + t) * TT + tg];
        if (t == 0) sc += start_t[tg] + e;
        else        sc += trans[tb[t - 1] * TT + tg] + e;
    }
#pragma unroll
    for (int off = 32; off; off >>= 1) sc += __shfl_xor(sc, off);
    const float score = sc + end_t[tb[len - 1]];

    // alpha0 in exp space
    float v0 = start_t[jj] + emis[(size_t)b * SS * TT + jj];
    float m = v0; HALF_MAX(m);
    float A = __expf(v0 - m);
    float logoff = m;

#pragma unroll 1
    for (int cc = 0; cc < NC; ++cc) {
        const float* Pc = &P[((size_t)b * NC + cc) * 1024];
        float s0 = 0.f, s1 = 0.f, s2 = 0.f, s3 = 0.f;
#pragma unroll
        for (int i = 0; i < 32; i += 4) {
            s0 = fmaf(rl(A, i+0), Pc[(i+0)*32 + jj], s0);
            s1 = fmaf(rl(A, i+1), Pc[(i+1)*32 + jj], s1);
            s2 = fmaf(rl(A, i+2), Pc[(i+2)*32 + jj], s2);
            s3 = fmaf(rl(A, i+3), Pc[(i+3)*32 + jj], s3);
        }
        float S = (s0 + s1) + (s2 + s3);
        float M = S; HALF_MAX(M);
        A = S * __builtin_amdgcn_rcpf(M);
        logoff += __logf(M) + Ls[b * NC + cc];
    }

    float z = A * __expf(end_t[jj]);
    HALF_SUM(z);
    const float log_z = logoff + __logf(z);

    if (lane == 0)
        atomicAdd(out, (log_z - score) * (1.0f / BB));
}

// ---------------------------------------------------------------------------
extern "C" void kernel_launch(void* const* d_in, const int* in_sizes, int n_in,
                              void* d_out, int out_size, void* d_ws, size_t ws_size,
                              hipStream_t stream) {
    const float* feat = (const float*)d_in[0];
    const int*   tags = (const int*)  d_in[1];
    const float* W    = (const float*)d_in[2];
    const float* bias = (const float*)d_in[3];
    const float* st   = (const float*)d_in[4];
    const float* en   = (const float*)d_in[5];
    const float* tr   = (const float*)d_in[6];
    float* out  = (float*)d_out;
    float* emis = (float*)d_ws;                        // 4 MB
    float* P    = emis + (size_t)MM * TT;              // 8 MB (64*32*32*32)
    float* Ls   = P + (size_t)BB * NC * 32 * 32;       // 8 KB

    (void)hipMemsetAsync(out, 0, sizeof(float), stream);
    gemm_emit<<<MM / 64, 256, 0, stream>>>(feat, W, bias, emis);
    crf_phase1<<<BB * 8, 128, 0, stream>>>(emis, tags, tr, P, Ls);
    crf_phase2<<<BB, 64, 0, stream>>>(emis, tags, st, en, tr, P, Ls, out);
}